// Round 1
// baseline (2488.520 us; speedup 1.0000x reference)
//
#include <hip/hip_runtime.h>
#include <hip/hip_bf16.h>

// GraphSAGE: 2x SAGEConv(mean) + linear head. N=40000, E=640000, D=128.
// Round 1: correct fp32 baseline. Aggregation via HW fp32 atomics; fused
// dual-GEMM conv kernel (agg@Wl + b + x@Wr, relu) with LDS tiling.

#define DH 128
#define BM 64
#define BK 32

__global__ void deg_kernel(const int* __restrict__ dst, float* __restrict__ deg, int E) {
    int i = blockIdx.x * blockDim.x + threadIdx.x;
    if (i < E) unsafeAtomicAdd(&deg[dst[i]], 1.0f);
}

__global__ void inv_kernel(float* __restrict__ deg, int N) {
    int i = blockIdx.x * blockDim.x + threadIdx.x;
    if (i < N) deg[i] = 1.0f / fmaxf(deg[i], 1.0f);
}

// One thread handles (edge, 4-dim chunk): float4 gather + 4 scalar atomics.
__global__ __launch_bounds__(256) void scatter_kernel(
    const float* __restrict__ feat, const int* __restrict__ srcs,
    const int* __restrict__ dsts, float* __restrict__ out, int E)
{
    int idx = blockIdx.x * blockDim.x + threadIdx.x;
    int e = idx >> 5;          // 32 threads per edge (128 dims / 4)
    int c = idx & 31;
    if (e >= E) return;
    int s = srcs[e];
    int d = dsts[e];
    float4 v = *(const float4*)&feat[(size_t)s * DH + c * 4];
    float* o = &out[(size_t)d * DH + c * 4];
    unsafeAtomicAdd(o + 0, v.x);
    unsafeAtomicAdd(o + 1, v.y);
    unsafeAtomicAdd(o + 2, v.z);
    unsafeAtomicAdd(o + 3, v.w);
}

// H[i,:] = relu( invdeg[i]*(Asum[i,:] @ Wl) + bias + X[i,:] @ Wr )
// Block: 256 threads, 64 rows x 128 cols tile. Safe for H aliasing Asum or X
// (each block reads only its own 64 rows, writes them only in the epilogue).
__global__ __launch_bounds__(256) void sage_conv_kernel(
    const float* __restrict__ Asum, const float* __restrict__ invdeg,
    const float* __restrict__ X,
    const float* __restrict__ Wl, const float* __restrict__ bias,
    const float* __restrict__ Wr, float* __restrict__ H)
{
    __shared__ float As[BM][BK];    // 8 KB
    __shared__ float Ws[BK][DH];    // 16 KB
    const int tid = threadIdx.x;
    const int row0 = blockIdx.x * BM;
    const int tm = tid >> 5;        // 0..7  (8 rows each)
    const int tn = tid & 31;        // 0..31 (4 cols each)

    float acc[8][4];
    #pragma unroll
    for (int r = 0; r < 8; ++r)
        for (int j = 0; j < 4; ++j) acc[r][j] = 0.0f;

    for (int p = 0; p < 2; ++p) {
        const float* A = p ? X : Asum;
        const float* W = p ? Wr : Wl;
        for (int kk = 0; kk < DH; kk += BK) {
            __syncthreads();
            // stage A tile: 64 rows x 32 cols = 512 float4
            #pragma unroll
            for (int l = tid; l < 512; l += 256) {
                int row = l >> 3;
                int c4 = l & 7;
                float4 v = *(const float4*)&A[(size_t)(row0 + row) * DH + kk + c4 * 4];
                if (p == 0) {
                    float s = invdeg[row0 + row];
                    v.x *= s; v.y *= s; v.z *= s; v.w *= s;
                }
                *(float4*)&As[row][c4 * 4] = v;
            }
            // stage W tile: 32 rows x 128 cols = 1024 float4
            #pragma unroll
            for (int l = tid; l < 1024; l += 256) {
                float4 v = *(const float4*)&W[kk * DH + l * 4];
                *(float4*)&Ws[0][l * 4] = v;
            }
            __syncthreads();
            #pragma unroll
            for (int k4 = 0; k4 < BK; k4 += 4) {
                float4 w0 = *(const float4*)&Ws[k4 + 0][tn * 4];
                float4 w1 = *(const float4*)&Ws[k4 + 1][tn * 4];
                float4 w2 = *(const float4*)&Ws[k4 + 2][tn * 4];
                float4 w3 = *(const float4*)&Ws[k4 + 3][tn * 4];
                #pragma unroll
                for (int r = 0; r < 8; ++r) {
                    float4 a = *(const float4*)&As[tm * 8 + r][k4];
                    acc[r][0] += a.x * w0.x + a.y * w1.x + a.z * w2.x + a.w * w3.x;
                    acc[r][1] += a.x * w0.y + a.y * w1.y + a.z * w2.y + a.w * w3.y;
                    acc[r][2] += a.x * w0.z + a.y * w1.z + a.z * w2.z + a.w * w3.z;
                    acc[r][3] += a.x * w0.w + a.y * w1.w + a.z * w2.w + a.w * w3.w;
                }
            }
        }
    }
    float4 bv = *(const float4*)&bias[tn * 4];
    #pragma unroll
    for (int r = 0; r < 8; ++r) {
        float4 o;
        o.x = fmaxf(acc[r][0] + bv.x, 0.0f);
        o.y = fmaxf(acc[r][1] + bv.y, 0.0f);
        o.z = fmaxf(acc[r][2] + bv.z, 0.0f);
        o.w = fmaxf(acc[r][3] + bv.w, 0.0f);
        *(float4*)&H[(size_t)(row0 + tm * 8 + r) * DH + tn * 4] = o;
    }
}

// out[i] = H[i,:] . Wo + bo   — one wave per row.
__global__ __launch_bounds__(256) void out_kernel(
    const float* __restrict__ H, const float* __restrict__ Wo,
    const float* __restrict__ bo, float* __restrict__ out, int N)
{
    int row = blockIdx.x * 4 + (threadIdx.x >> 6);
    int lane = threadIdx.x & 63;
    if (row >= N) return;
    float2 h = *(const float2*)&H[(size_t)row * DH + lane * 2];
    float2 w = *(const float2*)&Wo[lane * 2];
    float v = h.x * w.x + h.y * w.y;
    #pragma unroll
    for (int off = 32; off; off >>= 1) v += __shfl_down(v, off);
    if (lane == 0) out[row] = v + bo[0];
}

extern "C" void kernel_launch(void* const* d_in, const int* in_sizes, int n_in,
                              void* d_out, int out_size, void* d_ws, size_t ws_size,
                              hipStream_t stream) {
    const float* x   = (const float*)d_in[0];
    const int*   ei  = (const int*)d_in[1];
    const float* W1l = (const float*)d_in[2];
    const float* b1  = (const float*)d_in[3];
    const float* W1r = (const float*)d_in[4];
    const float* W2l = (const float*)d_in[5];
    const float* b2  = (const float*)d_in[6];
    const float* W2r = (const float*)d_in[7];
    const float* Wo  = (const float*)d_in[8];
    const float* bo  = (const float*)d_in[9];
    float* out = (float*)d_out;

    const int N = in_sizes[0] / DH;      // 40000
    const int E = in_sizes[1] / 2;       // 640000
    const int* src = ei;
    const int* dst = ei + E;

    float* ws  = (float*)d_ws;
    float* deg = ws;                     // N floats (becomes invdeg)
    float* A   = ws + N;                 // N*128 (agg sums; later h2 in-place)
    float* B   = A + (size_t)N * DH;     // N*128 (h1)

    const size_t featBytes = (size_t)N * DH * sizeof(float);

    // conv1 aggregation
    hipMemsetAsync(deg, 0, (size_t)N * sizeof(float), stream);
    hipMemsetAsync(A, 0, featBytes, stream);
    deg_kernel<<<(E + 255) / 256, 256, 0, stream>>>(dst, deg, E);
    inv_kernel<<<(N + 255) / 256, 256, 0, stream>>>(deg, N);
    scatter_kernel<<<(E * 32 + 255) / 256, 256, 0, stream>>>(x, src, dst, A, E);
    // h1 = relu(invdeg*A @ W1l + b1 + x @ W1r)
    sage_conv_kernel<<<N / BM, 256, 0, stream>>>(A, deg, x, W1l, b1, W1r, B);

    // conv2 aggregation (re-zero A, scatter h1)
    hipMemsetAsync(A, 0, featBytes, stream);
    scatter_kernel<<<(E * 32 + 255) / 256, 256, 0, stream>>>(B, src, dst, A, E);
    // h2 = relu(invdeg*A @ W2l + b2 + h1 @ W2r)  — written in place over A (safe)
    sage_conv_kernel<<<N / BM, 256, 0, stream>>>(A, deg, B, W2l, b2, W2r, A);

    // out = h2 @ Wo + bo
    out_kernel<<<(N + 3) / 4, 256, 0, stream>>>(A, Wo, bo, out, N);
}

// Round 2
// 426.935 us; speedup vs baseline: 5.8288x; 5.8288x over previous
//
#include <hip/hip_runtime.h>
#include <hip/hip_bf16.h>

// GraphSAGE: 2x SAGEConv(mean) + linear head. N=40000, E=640000, D=128.
// Round 2: kill the fp32 atomic scatter (was 87% of runtime, atomic-throughput
// bound at 76G atomics/s). Build CSR (histogram + 2-level scan + fill, ~1.3M
// int atomics) then gather-mean with one wave per node.

#define DH 128

// ---------------- CSR build ----------------

__global__ void deg_kernel(const int* __restrict__ dst, int* __restrict__ deg, int E) {
    int i = blockIdx.x * blockDim.x + threadIdx.x;
    if (i < E) atomicAdd(&deg[dst[i]], 1);
}

// Per-block Hillis-Steele scan: exclusive offsets within block + block sums.
__global__ __launch_bounds__(256) void scan1_kernel(
    const int* __restrict__ deg, int* __restrict__ offs, int* __restrict__ bsum, int N)
{
    __shared__ int tmp[256];
    int tid = threadIdx.x;
    int i = blockIdx.x * 256 + tid;
    int v = (i < N) ? deg[i] : 0;
    tmp[tid] = v;
    __syncthreads();
    #pragma unroll
    for (int off = 1; off < 256; off <<= 1) {
        int t = (tid >= off) ? tmp[tid - off] : 0;
        __syncthreads();
        tmp[tid] += t;
        __syncthreads();
    }
    if (i < N) offs[i] = tmp[tid] - v;      // exclusive
    if (tid == 255) bsum[blockIdx.x] = tmp[255];
}

// Scan the (<=256) block sums. One block.
__global__ __launch_bounds__(256) void scan2_kernel(
    const int* __restrict__ bsum, int* __restrict__ boffs, int nb)
{
    __shared__ int tmp[256];
    int tid = threadIdx.x;
    int v = (tid < nb) ? bsum[tid] : 0;
    tmp[tid] = v;
    __syncthreads();
    #pragma unroll
    for (int off = 1; off < 256; off <<= 1) {
        int t = (tid >= off) ? tmp[tid - off] : 0;
        __syncthreads();
        tmp[tid] += t;
        __syncthreads();
    }
    if (tid < nb) boffs[tid] = tmp[tid] - v;  // exclusive
}

__global__ void fill_kernel(const int* __restrict__ src, const int* __restrict__ dst,
                            const int* __restrict__ offs, const int* __restrict__ boffs,
                            int* __restrict__ cursor, int* __restrict__ csr, int E)
{
    int e = blockIdx.x * blockDim.x + threadIdx.x;
    if (e >= E) return;
    int d = dst[e];
    int pos = atomicAdd(&cursor[d], 1);
    csr[offs[d] + boffs[d >> 8] + pos] = src[e];
}

// ---------------- gather: out[n,:] = mean over incoming src of feat[src,:] ----
// One wave per node. 32 lanes cover the 128-dim row as float4; the two 32-lane
// halves take alternate edges; 2-deep unroll per half breaks the acc dep chain.

__device__ __forceinline__ void f4add(float4& a, const float4 b) {
    a.x += b.x; a.y += b.y; a.z += b.z; a.w += b.w;
}

__global__ __launch_bounds__(256) void gather_mean_kernel(
    const float* __restrict__ feat, const int* __restrict__ csr,
    const int* __restrict__ offs, const int* __restrict__ boffs,
    const int* __restrict__ deg, float* __restrict__ out, int N)
{
    int node = blockIdx.x * 4 + (threadIdx.x >> 6);
    if (node >= N) return;
    int lane = threadIdx.x & 63;
    int c = lane & 31;
    int half = lane >> 5;

    int start = offs[node] + boffs[node >> 8];
    int dg = deg[node];
    int end = start + dg;

    float4 a0 = make_float4(0.f, 0.f, 0.f, 0.f);
    float4 a1 = make_float4(0.f, 0.f, 0.f, 0.f);
    int e = start + half;
    for (; e + 2 < end; e += 4) {
        int s0 = csr[e];
        int s1 = csr[e + 2];
        f4add(a0, *(const float4*)&feat[(size_t)s0 * DH + c * 4]);
        f4add(a1, *(const float4*)&feat[(size_t)s1 * DH + c * 4]);
    }
    if (e < end) f4add(a0, *(const float4*)&feat[(size_t)csr[e] * DH + c * 4]);
    f4add(a0, a1);
    // combine the two halves (lane l += lane l+32)
    a0.x += __shfl_down(a0.x, 32);
    a0.y += __shfl_down(a0.y, 32);
    a0.z += __shfl_down(a0.z, 32);
    a0.w += __shfl_down(a0.w, 32);
    if (half == 0) {
        float sc = 1.0f / (float)max(dg, 1);
        a0.x *= sc; a0.y *= sc; a0.z *= sc; a0.w *= sc;
        *(float4*)&out[(size_t)node * DH + c * 4] = a0;
    }
}

// ---------------- fused SAGE conv: H = relu(Agg@Wl + b + X@Wr) ----------------
// Agg already holds the per-node MEAN. Safe for H aliasing Agg or X (each block
// reads only its own 64 rows before writing them in the epilogue).

#define BM 64
#define BK 32

__global__ __launch_bounds__(256) void sage_conv_kernel(
    const float* __restrict__ Agg, const float* __restrict__ X,
    const float* __restrict__ Wl, const float* __restrict__ bias,
    const float* __restrict__ Wr, float* __restrict__ H)
{
    __shared__ float As[BM][BK];    // 8 KB
    __shared__ float Ws[BK][DH];    // 16 KB
    const int tid = threadIdx.x;
    const int row0 = blockIdx.x * BM;
    const int tm = tid >> 5;        // 0..7  (8 rows each)
    const int tn = tid & 31;        // 0..31 (4 cols each)

    float acc[8][4];
    #pragma unroll
    for (int r = 0; r < 8; ++r)
        for (int j = 0; j < 4; ++j) acc[r][j] = 0.0f;

    for (int p = 0; p < 2; ++p) {
        const float* A = p ? X : Agg;
        const float* W = p ? Wr : Wl;
        for (int kk = 0; kk < DH; kk += BK) {
            __syncthreads();
            #pragma unroll
            for (int l = tid; l < 512; l += 256) {
                int row = l >> 3;
                int c4 = l & 7;
                *(float4*)&As[row][c4 * 4] =
                    *(const float4*)&A[(size_t)(row0 + row) * DH + kk + c4 * 4];
            }
            #pragma unroll
            for (int l = tid; l < 1024; l += 256) {
                *(float4*)&Ws[0][l * 4] = *(const float4*)&W[kk * DH + l * 4];
            }
            __syncthreads();
            #pragma unroll
            for (int k4 = 0; k4 < BK; k4 += 4) {
                float4 w0 = *(const float4*)&Ws[k4 + 0][tn * 4];
                float4 w1 = *(const float4*)&Ws[k4 + 1][tn * 4];
                float4 w2 = *(const float4*)&Ws[k4 + 2][tn * 4];
                float4 w3 = *(const float4*)&Ws[k4 + 3][tn * 4];
                #pragma unroll
                for (int r = 0; r < 8; ++r) {
                    float4 a = *(const float4*)&As[tm * 8 + r][k4];
                    acc[r][0] += a.x * w0.x + a.y * w1.x + a.z * w2.x + a.w * w3.x;
                    acc[r][1] += a.x * w0.y + a.y * w1.y + a.z * w2.y + a.w * w3.y;
                    acc[r][2] += a.x * w0.z + a.y * w1.z + a.z * w2.z + a.w * w3.z;
                    acc[r][3] += a.x * w0.w + a.y * w1.w + a.z * w2.w + a.w * w3.w;
                }
            }
        }
    }
    float4 bv = *(const float4*)&bias[tn * 4];
    #pragma unroll
    for (int r = 0; r < 8; ++r) {
        float4 o;
        o.x = fmaxf(acc[r][0] + bv.x, 0.0f);
        o.y = fmaxf(acc[r][1] + bv.y, 0.0f);
        o.z = fmaxf(acc[r][2] + bv.z, 0.0f);
        o.w = fmaxf(acc[r][3] + bv.w, 0.0f);
        *(float4*)&H[(size_t)(row0 + tm * 8 + r) * DH + tn * 4] = o;
    }
}

// out[i] = H[i,:] . Wo + bo — one wave per row.
__global__ __launch_bounds__(256) void out_kernel(
    const float* __restrict__ H, const float* __restrict__ Wo,
    const float* __restrict__ bo, float* __restrict__ out, int N)
{
    int row = blockIdx.x * 4 + (threadIdx.x >> 6);
    int lane = threadIdx.x & 63;
    if (row >= N) return;
    float2 h = *(const float2*)&H[(size_t)row * DH + lane * 2];
    float2 w = *(const float2*)&Wo[lane * 2];
    float v = h.x * w.x + h.y * w.y;
    #pragma unroll
    for (int off = 32; off; off >>= 1) v += __shfl_down(v, off);
    if (lane == 0) out[row] = v + bo[0];
}

extern "C" void kernel_launch(void* const* d_in, const int* in_sizes, int n_in,
                              void* d_out, int out_size, void* d_ws, size_t ws_size,
                              hipStream_t stream) {
    const float* x   = (const float*)d_in[0];
    const int*   ei  = (const int*)d_in[1];
    const float* W1l = (const float*)d_in[2];
    const float* b1  = (const float*)d_in[3];
    const float* W1r = (const float*)d_in[4];
    const float* W2l = (const float*)d_in[5];
    const float* b2  = (const float*)d_in[6];
    const float* W2r = (const float*)d_in[7];
    const float* Wo  = (const float*)d_in[8];
    const float* bo  = (const float*)d_in[9];
    float* out = (float*)d_out;

    const int N = in_sizes[0] / DH;      // 40000
    const int E = in_sizes[1] / 2;       // 640000
    const int* src = ei;
    const int* dst = ei + E;
    const int nb = (N + 255) / 256;      // scan blocks (<=256)

    // workspace layout
    float* A = (float*)d_ws;                       // N*128 (agg means; later h2)
    float* B = A + (size_t)N * DH;                 // N*128 (h1)
    int* deg    = (int*)(B + (size_t)N * DH);      // N
    int* offs   = deg + N;                         // N
    int* cursor = offs + N;                        // N
    int* bsum   = cursor + N;                      // 256
    int* boffs  = bsum + 256;                      // 256
    int* csr    = boffs + 256;                     // E

    // ---- CSR build (graph shared by both convs) ----
    hipMemsetAsync(deg, 0, (size_t)N * sizeof(int), stream);
    hipMemsetAsync(cursor, 0, (size_t)N * sizeof(int), stream);
    deg_kernel<<<(E + 255) / 256, 256, 0, stream>>>(dst, deg, E);
    scan1_kernel<<<nb, 256, 0, stream>>>(deg, offs, bsum, N);
    scan2_kernel<<<1, 256, 0, stream>>>(bsum, boffs, nb);
    fill_kernel<<<(E + 255) / 256, 256, 0, stream>>>(src, dst, offs, boffs, cursor, csr, E);

    // ---- layer 1 ----
    gather_mean_kernel<<<(N + 3) / 4, 256, 0, stream>>>(x, csr, offs, boffs, deg, A, N);
    sage_conv_kernel<<<N / BM, 256, 0, stream>>>(A, x, W1l, b1, W1r, B);

    // ---- layer 2 ----
    gather_mean_kernel<<<(N + 3) / 4, 256, 0, stream>>>(B, csr, offs, boffs, deg, A, N);
    sage_conv_kernel<<<N / BM, 256, 0, stream>>>(A, B, W2l, b2, W2r, A);

    // ---- head ----
    out_kernel<<<(N + 3) / 4, 256, 0, stream>>>(A, Wo, bo, out, N);
}

// Round 3
// 288.336 us; speedup vs baseline: 8.6306x; 1.4807x over previous
//
#include <hip/hip_runtime.h>
#include <hip/hip_bf16.h>

// GraphSAGE: 2x SAGEConv(mean) + linear head. N=40000, E=640000, D=128.
// Round 3: conv GEMMs via bf16x3 split-precision MFMA (error ~2^-17, fits the
// 9.7e-3 threshold with fp32-like margin). Conv = single [Agg|X](K=256) GEMM,
// LDS-free/barrier-free: W pre-split into MFMA-fragment layout once (wprep),
// A converted hi/lo in-register. CSR + gather-mean unchanged from round 2.

#define DH 128

typedef __attribute__((ext_vector_type(8))) short bf16x8;
typedef __attribute__((ext_vector_type(4))) float f32x4;

__device__ __forceinline__ unsigned short f2bf_rne(float f) {
    unsigned int u = __float_as_uint(f);
    return (unsigned short)((u + 0x7FFFu + ((u >> 16) & 1u)) >> 16);
}
__device__ __forceinline__ float bf2f(unsigned short h) {
    return __uint_as_float(((unsigned int)h) << 16);
}

// ---------------- CSR build ----------------

__global__ void deg_kernel(const int* __restrict__ dst, int* __restrict__ deg, int E) {
    int i = blockIdx.x * blockDim.x + threadIdx.x;
    if (i < E) atomicAdd(&deg[dst[i]], 1);
}

__global__ __launch_bounds__(256) void scan1_kernel(
    const int* __restrict__ deg, int* __restrict__ offs, int* __restrict__ bsum, int N)
{
    __shared__ int tmp[256];
    int tid = threadIdx.x;
    int i = blockIdx.x * 256 + tid;
    int v = (i < N) ? deg[i] : 0;
    tmp[tid] = v;
    __syncthreads();
    #pragma unroll
    for (int off = 1; off < 256; off <<= 1) {
        int t = (tid >= off) ? tmp[tid - off] : 0;
        __syncthreads();
        tmp[tid] += t;
        __syncthreads();
    }
    if (i < N) offs[i] = tmp[tid] - v;
    if (tid == 255) bsum[blockIdx.x] = tmp[255];
}

__global__ __launch_bounds__(256) void scan2_kernel(
    const int* __restrict__ bsum, int* __restrict__ boffs, int nb)
{
    __shared__ int tmp[256];
    int tid = threadIdx.x;
    int v = (tid < nb) ? bsum[tid] : 0;
    tmp[tid] = v;
    __syncthreads();
    #pragma unroll
    for (int off = 1; off < 256; off <<= 1) {
        int t = (tid >= off) ? tmp[tid - off] : 0;
        __syncthreads();
        tmp[tid] += t;
        __syncthreads();
    }
    if (tid < nb) boffs[tid] = tmp[tid] - v;
}

__global__ void fill_kernel(const int* __restrict__ src, const int* __restrict__ dst,
                            const int* __restrict__ offs, const int* __restrict__ boffs,
                            int* __restrict__ cursor, int* __restrict__ csr, int E)
{
    int e = blockIdx.x * blockDim.x + threadIdx.x;
    if (e >= E) return;
    int d = dst[e];
    int pos = atomicAdd(&cursor[d], 1);
    csr[offs[d] + boffs[d >> 8] + pos] = src[e];
}

// ---------------- gather mean (one wave per node) ----------------

__device__ __forceinline__ void f4add(float4& a, const float4 b) {
    a.x += b.x; a.y += b.y; a.z += b.z; a.w += b.w;
}

__global__ __launch_bounds__(256) void gather_mean_kernel(
    const float* __restrict__ feat, const int* __restrict__ csr,
    const int* __restrict__ offs, const int* __restrict__ boffs,
    const int* __restrict__ deg, float* __restrict__ out, int N)
{
    int node = blockIdx.x * 4 + (threadIdx.x >> 6);
    if (node >= N) return;
    int lane = threadIdx.x & 63;
    int c = lane & 31;
    int half = lane >> 5;

    int start = offs[node] + boffs[node >> 8];
    int dg = deg[node];
    int end = start + dg;

    float4 a0 = make_float4(0.f, 0.f, 0.f, 0.f);
    float4 a1 = make_float4(0.f, 0.f, 0.f, 0.f);
    int e = start + half;
    for (; e + 2 < end; e += 4) {
        int s0 = csr[e];
        int s1 = csr[e + 2];
        f4add(a0, *(const float4*)&feat[(size_t)s0 * DH + c * 4]);
        f4add(a1, *(const float4*)&feat[(size_t)s1 * DH + c * 4]);
    }
    if (e < end) f4add(a0, *(const float4*)&feat[(size_t)csr[e] * DH + c * 4]);
    f4add(a0, a1);
    a0.x += __shfl_down(a0.x, 32);
    a0.y += __shfl_down(a0.y, 32);
    a0.z += __shfl_down(a0.z, 32);
    a0.w += __shfl_down(a0.w, 32);
    if (half == 0) {
        float sc = 1.0f / (float)max(dg, 1);
        a0.x *= sc; a0.y *= sc; a0.z *= sc; a0.w *= sc;
        *(float4*)&out[(size_t)node * DH + c * 4] = a0;
    }
}

// ---------------- W pre-split: fragment-ready bf16 hi/lo ----------------
// B = [Wl ; Wr] (256x128). Fragment layout for v_mfma_f32_16x16x32_bf16:
// lane l supplies B[k = t*32 + (l>>4)*8 + j][col = f*16 + (l&15)], j=0..7.
// Stored as hi/lo[conv][t][f][lane][j] so conv loads are 16B/lane coalesced.

__global__ __launch_bounds__(256) void wprep_kernel(
    const float* __restrict__ W1l, const float* __restrict__ W1r,
    const float* __restrict__ W2l, const float* __restrict__ W2r,
    unsigned short* __restrict__ whi, unsigned short* __restrict__ wlo)
{
    int tid = blockIdx.x * 256 + threadIdx.x;       // [conv][t][f][lane]
    if (tid >= 2 * 8 * 8 * 64) return;
    int lane = tid & 63;
    int f = (tid >> 6) & 7;
    int t = (tid >> 9) & 7;
    int conv = tid >> 12;
    const float* Wl = conv ? W2l : W1l;
    const float* Wr = conv ? W2r : W1r;
    int c = f * 16 + (lane & 15);
    int kb = t * 32 + (lane >> 4) * 8;
    size_t off = (size_t)tid * 8;
    #pragma unroll
    for (int j = 0; j < 8; ++j) {
        int k = kb + j;
        float w = (k < 128) ? Wl[k * 128 + c] : Wr[(k - 128) * 128 + c];
        unsigned short h = f2bf_rne(w);
        whi[off + j] = h;
        wlo[off + j] = f2bf_rne(w - bf2f(h));
    }
}

// ---------------- fused SAGE conv via MFMA ----------------
// H = relu([Agg | X] @ [Wl; Wr] + bias), bf16x3. 4 waves/block, 16 rows/wave.
// No LDS, no barriers. In-place safe: each wave reads only the rows it writes,
// all reads precede its stores.

__global__ __launch_bounds__(256) void sage_mfma_kernel(
    const float* __restrict__ Agg, const float* __restrict__ X,
    const unsigned short* __restrict__ whi, const unsigned short* __restrict__ wlo,
    const float* __restrict__ bias, float* __restrict__ H)
{
    const int l = threadIdx.x & 63;
    const int wv = threadIdx.x >> 6;
    const int row0 = blockIdx.x * 64 + wv * 16;
    const int r = l & 15;
    const int kq = l >> 4;          // 0..3

    f32x4 acc[8];
    #pragma unroll
    for (int f = 0; f < 8; ++f) {
        float b = bias[f * 16 + r];
        acc[f] = (f32x4){b, b, b, b};
    }

    #pragma unroll
    for (int t = 0; t < 8; ++t) {
        const float* A = (t < 4) ? Agg : X;
        const float* ap = &A[(size_t)(row0 + r) * DH + (t & 3) * 32 + kq * 8];
        float4 f0 = *(const float4*)ap;
        float4 f1 = *(const float4*)(ap + 4);
        float a[8] = {f0.x, f0.y, f0.z, f0.w, f1.x, f1.y, f1.z, f1.w};
        bf16x8 ahi, alo;
        #pragma unroll
        for (int j = 0; j < 8; ++j) {
            unsigned short h = f2bf_rne(a[j]);
            ahi[j] = (short)h;
            alo[j] = (short)f2bf_rne(a[j] - bf2f(h));
        }
        const unsigned short* bh = whi + ((size_t)(t * 8) * 64 + l) * 8;
        const unsigned short* bl = wlo + ((size_t)(t * 8) * 64 + l) * 8;
        #pragma unroll
        for (int f = 0; f < 8; ++f) {
            bf16x8 bhi = *(const bf16x8*)(bh + (size_t)f * 64 * 8);
            bf16x8 blo = *(const bf16x8*)(bl + (size_t)f * 64 * 8);
            acc[f] = __builtin_amdgcn_mfma_f32_16x16x32_bf16(ahi, bhi, acc[f], 0, 0, 0);
            acc[f] = __builtin_amdgcn_mfma_f32_16x16x32_bf16(alo, bhi, acc[f], 0, 0, 0);
            acc[f] = __builtin_amdgcn_mfma_f32_16x16x32_bf16(ahi, blo, acc[f], 0, 0, 0);
        }
    }

    #pragma unroll
    for (int f = 0; f < 8; ++f) {
        int col = f * 16 + r;
        #pragma unroll
        for (int q = 0; q < 4; ++q) {
            int row = row0 + kq * 4 + q;
            H[(size_t)row * DH + col] = fmaxf(acc[f][q], 0.0f);
        }
    }
}

// out[i] = H[i,:] . Wo + bo — one wave per row.
__global__ __launch_bounds__(256) void out_kernel(
    const float* __restrict__ H, const float* __restrict__ Wo,
    const float* __restrict__ bo, float* __restrict__ out, int N)
{
    int row = blockIdx.x * 4 + (threadIdx.x >> 6);
    int lane = threadIdx.x & 63;
    if (row >= N) return;
    float2 h = *(const float2*)&H[(size_t)row * DH + lane * 2];
    float2 w = *(const float2*)&Wo[lane * 2];
    float v = h.x * w.x + h.y * w.y;
    #pragma unroll
    for (int off = 32; off; off >>= 1) v += __shfl_down(v, off);
    if (lane == 0) out[row] = v + bo[0];
}

extern "C" void kernel_launch(void* const* d_in, const int* in_sizes, int n_in,
                              void* d_out, int out_size, void* d_ws, size_t ws_size,
                              hipStream_t stream) {
    const float* x   = (const float*)d_in[0];
    const int*   ei  = (const int*)d_in[1];
    const float* W1l = (const float*)d_in[2];
    const float* b1  = (const float*)d_in[3];
    const float* W1r = (const float*)d_in[4];
    const float* W2l = (const float*)d_in[5];
    const float* b2  = (const float*)d_in[6];
    const float* W2r = (const float*)d_in[7];
    const float* Wo  = (const float*)d_in[8];
    const float* bo  = (const float*)d_in[9];
    float* out = (float*)d_out;

    const int N = in_sizes[0] / DH;      // 40000
    const int E = in_sizes[1] / 2;       // 640000
    const int* src = ei;
    const int* dst = ei + E;
    const int nb = (N + 255) / 256;

    // workspace layout (all chunks 16B-multiple)
    float* A = (float*)d_ws;                       // N*128
    float* B = A + (size_t)N * DH;                 // N*128
    int* deg    = (int*)(B + (size_t)N * DH);      // N
    int* offs   = deg + N;                         // N
    int* cursor = offs + N;                        // N
    int* bsum   = cursor + N;                      // 256
    int* boffs  = bsum + 256;                      // 256
    int* csr    = boffs + 256;                     // E
    unsigned short* whi = (unsigned short*)(csr + E);  // 2*32768
    unsigned short* wlo = whi + 2 * 32768;             // 2*32768

    // ---- CSR build + W pre-split ----
    hipMemsetAsync(deg, 0, (size_t)N * sizeof(int), stream);
    hipMemsetAsync(cursor, 0, (size_t)N * sizeof(int), stream);
    deg_kernel<<<(E + 255) / 256, 256, 0, stream>>>(dst, deg, E);
    wprep_kernel<<<32, 256, 0, stream>>>(W1l, W1r, W2l, W2r, whi, wlo);
    scan1_kernel<<<nb, 256, 0, stream>>>(deg, offs, bsum, N);
    scan2_kernel<<<1, 256, 0, stream>>>(bsum, boffs, nb);
    fill_kernel<<<(E + 255) / 256, 256, 0, stream>>>(src, dst, offs, boffs, cursor, csr, E);

    // ---- layer 1 ----
    gather_mean_kernel<<<(N + 3) / 4, 256, 0, stream>>>(x, csr, offs, boffs, deg, A, N);
    sage_mfma_kernel<<<N / 64, 256, 0, stream>>>(A, x, whi, wlo, b1, B);

    // ---- layer 2 ----
    gather_mean_kernel<<<(N + 3) / 4, 256, 0, stream>>>(B, csr, offs, boffs, deg, A, N);
    sage_mfma_kernel<<<N / 64, 256, 0, stream>>>(A, B, whi + 32768, wlo + 32768, b2, A);

    // ---- head ----
    out_kernel<<<(N + 3) / 4, 256, 0, stream>>>(A, Wo, bo, out, N);
}